// Round 10
// baseline (420.334 us; speedup 1.0000x reference)
//
#include <hip/hip_runtime.h>
#include <math.h>

#define NEG_SLOPE 0.2f
#define EPSV 1e-16f
#define NPART 8

typedef _Float16 half4 __attribute__((ext_vector_type(4)));
typedef _Float16 half8 __attribute__((ext_vector_type(8)));
typedef float f32x4 __attribute__((ext_vector_type(4)));

// ---------------- CSR build ----------------

// block scan over 1024-node chunks; deg computed inline from degp; bsum = raw chunk sum
__global__ void k_scan_blk(const int* __restrict__ degp, int N,
                           int* __restrict__ rowptr, int* __restrict__ bsum){
    int b = blockIdx.x, t = threadIdx.x;
    int base = b * 1024 + t * 4;
    int v[4];
    #pragma unroll
    for (int j = 0; j < 4; j++){
        int n = base + j, s = 0;
        if (n < N){
            #pragma unroll
            for (int p = 0; p < NPART; p++) s += degp[p * N + n];
        }
        v[j] = s;
    }
    int s = v[0] + v[1] + v[2] + v[3];
    int lane = t & 63, wid = t >> 6;
    int x = s;
    #pragma unroll
    for (int off = 1; off < 64; off <<= 1){
        int y = __shfl_up(x, off, 64);
        if (lane >= off) x += y;
    }
    __shared__ int ws[4];
    if (lane == 63) ws[wid] = x;
    __syncthreads();
    int woff = 0;
    for (int w = 0; w < wid; w++) woff += ws[w];
    int run = woff + x - s;
    #pragma unroll
    for (int j = 0; j < 4; j++){
        if (base + j < N) rowptr[base + j] = run;
        run += v[j];
    }
    if (t == 255) bsum[b] = woff + x;
}

// rowptr += prefix(bsum); cursor[p][n] = rowptr[n] + prefix_p(degp[.][n])
// cursor is MUTATED by k_scatter_c (atomic slot allocation).
__global__ void k_finalize(const int* __restrict__ bsum, const int* __restrict__ degp,
                           int N, int ET,
                           int* __restrict__ rowptr, int* __restrict__ cursor){
    int b = blockIdx.x, t = threadIdx.x;
    int n = b * 256 + t;
    int chunk = (b * 256) >> 10;           // wave-uniform
    int off = 0;
    for (int c = 0; c < chunk; c++) off += bsum[c];
    if (n < N){
        int r = rowptr[n] + off;
        rowptr[n] = r;
        int run = r;
        #pragma unroll
        for (int p = 0; p < NPART; p++){
            cursor[p * N + n] = run;
            run += degp[p * N + n];
        }
    }
    if (n == 0) rowptr[N] = ET;
}

// ---------------- hist: FIRE-AND-FORGET atomics (no return, no rank array) -------------
// Partition p = (i>>10)&7 == blockIdx.x&7 — pure function of edge id, so the scatter can
// re-derive it and claim slots itself. hist's atomics have no data dependency -> waves
// stream through with zero vmcnt waits (round 7: MORE outstanding RETURNING atomics was
// null; the experiment here is removing the return entirely).

__launch_bounds__(256)
__global__ void k_hist(const int* __restrict__ ei, int E, int ET, int N,
                       unsigned int* __restrict__ degp){
    int t = threadIdx.x;
    int p = blockIdx.x & (NPART - 1);
    int base = blockIdx.x * 1024 + t;
    #pragma unroll
    for (int j = 0; j < 4; j++){
        int i = base + j * 256;
        if (i < ET){
            int d = (i < E) ? ei[E + i] : (i - E);   // self loops appended
            atomicAdd(&degp[(size_t)p * N + d], 1u);  // no return
        }
    }
}

// ---------------- scatter: returning atomic on cursor allocates the CSR slot -----------
// Full edge-parallel TLP hides the atomic round trip; scattered 4B csr_src write only.

__launch_bounds__(256)
__global__ void k_scatter_c(const int* __restrict__ ei, int E, int ET, int N,
                            int* __restrict__ cursor, int* __restrict__ csr_src){
    int i = blockIdx.x * 256 + threadIdx.x;
    if (i >= ET) return;
    int s, d;
    if (i < E){ s = ei[i]; d = ei[E + i]; } else { s = i - E; d = s; }
    int p = (i >> 10) & (NPART - 1);
    int pos = atomicAdd(&cursor[p * N + d], 1);
    csr_src[pos] = s;
}

// ---------------- Pack: W1 -> fp16 MFMA B-fragments; U = W1 @ [a_src | a_dst] ----------

__global__ void k_pack(const float* __restrict__ W1, const float* __restrict__ a_src,
                       const float* __restrict__ a_dst,
                       _Float16* __restrict__ W1f, _Float16* __restrict__ Uf){
    int b = blockIdx.x, t = threadIdx.x;
    if (b < 32){
        #pragma unroll
        for (int i = 0; i < 2; i++){
            int idx = t + 256 * i;                 // 0..511
            int jj = idx & 7, ln = idx >> 3;       // ln 0..63
            int kt = b & 3, ct = b >> 2;
            int k = kt * 32 + (ln >> 4) * 8 + jj;
            int col = ct * 16 + (ln & 15);
            W1f[b * 512 + idx] = (_Float16)W1[k * 128 + col];
        }
        return;
    }
    // b == 32: compute U[128][8] then pack Uf
    __shared__ float U[128 * 8];
    if (t < 128){
        #pragma unroll
        for (int h = 0; h < 4; h++){
            float s = 0.f, d = 0.f;
            for (int cc = 0; cc < 32; cc++){
                float w = W1[t * 128 + h * 32 + cc];
                s += w * a_src[h * 32 + cc];
                d += w * a_dst[h * 32 + cc];
            }
            U[t * 8 + h]     = s;
            U[t * 8 + h + 4] = d;
        }
    }
    __syncthreads();
    for (int idx = t; idx < 4 * 64 * 8; idx += 256){
        int jj = idx & 7, ln = (idx >> 3) & 63, kt = idx >> 9;
        int k = kt * 32 + (ln >> 4) * 8 + jj;
        int col = ln & 15;
        Uf[idx] = (_Float16)(col < 8 ? U[k * 8 + col] : 0.f);
    }
}

// ---------------- MFMA GEMM1: 64 nodes/block, 4 waves x 16 rows -------------------------

__launch_bounds__(256)
__global__ void k_gemm1(const float* __restrict__ x, const _Float16* __restrict__ W1f,
                        const _Float16* __restrict__ Uf,
                        _Float16* __restrict__ h1h, float* __restrict__ asrc1,
                        float* __restrict__ adst1, int N){
    int t = threadIdx.x;
    int w = t >> 6, lane = t & 63;
    int arow = blockIdx.x * 64 + w * 16 + (lane & 15);     // A-fragment row
    bool arow_ok = (arow < N);
    const float4* xr = (const float4*)&x[(size_t)(arow_ok ? arow : 0) << 7];
    const half8* Wf = (const half8*)W1f;
    const half8* Uv = (const half8*)Uf;

    f32x4 acc[8];
    #pragma unroll
    for (int c = 0; c < 8; c++) acc[c] = (f32x4)0.f;
    f32x4 accA = (f32x4)0.f;

    #pragma unroll
    for (int kt = 0; kt < 4; kt++){
        half8 af;
        if (arow_ok){
            float4 p0 = xr[kt * 8 + (lane >> 4) * 2];
            float4 p1 = xr[kt * 8 + (lane >> 4) * 2 + 1];
            af[0] = (_Float16)p0.x; af[1] = (_Float16)p0.y;
            af[2] = (_Float16)p0.z; af[3] = (_Float16)p0.w;
            af[4] = (_Float16)p1.x; af[5] = (_Float16)p1.y;
            af[6] = (_Float16)p1.z; af[7] = (_Float16)p1.w;
        } else {
            af[0] = (_Float16)0.f; af[1] = (_Float16)0.f;
            af[2] = (_Float16)0.f; af[3] = (_Float16)0.f;
            af[4] = (_Float16)0.f; af[5] = (_Float16)0.f;
            af[6] = (_Float16)0.f; af[7] = (_Float16)0.f;
        }
        #pragma unroll
        for (int ct = 0; ct < 8; ct++){
            half8 bf = Wf[(ct * 4 + kt) * 64 + lane];
            acc[ct] = __builtin_amdgcn_mfma_f32_16x16x32_f16(af, bf, acc[ct], 0, 0, 0);
        }
        half8 uf = Uv[kt * 64 + lane];
        accA = __builtin_amdgcn_mfma_f32_16x16x32_f16(af, uf, accA, 0, 0, 0);
    }

    // epilogue: lane l, reg r -> row=(l>>4)*4+r, col=l&15
    int g = lane >> 4, j = lane & 15;
    int rowbase = blockIdx.x * 64 + w * 16 + g * 4;
    #pragma unroll
    for (int r = 0; r < 4; r++){
        int n = rowbase + r;
        if (n >= N) continue;
        _Float16* hrow = &h1h[(size_t)n << 7];
        #pragma unroll
        for (int ct = 0; ct < 8; ct++)
            hrow[ct * 16 + j] = (_Float16)acc[ct][r];
        float av = accA[r];
        if (j < 4)            asrc1[n * 4 + j]       = av;
        else if (j < 8)       adst1[n * 4 + (j - 4)] = av;
    }
}

// ---------------- Aggregation L1: GROUP-PER-NODE, unroll-8, fma_mix accumulate ----------
// 16 lanes own one node. Per edge: asrc gather (L2-resident) || h1h row gather issue
// together (single hop); exp in-chain but 8-deep; accumulation via scalar
// fmaf((float)h, w, acc) -> v_fma_mix_f32 (no separate cvt pipeline).

__launch_bounds__(256)
__global__ void k_agg1(const int* __restrict__ rowptr, const int* __restrict__ csr_src,
                       const float* __restrict__ asrc1, const float* __restrict__ adst1,
                       const _Float16* __restrict__ h1h,
                       const float* __restrict__ b1, float* __restrict__ x2, int N){
    int t = threadIdx.x;
    int lane = t & 63;
    int g = lane >> 4, l = lane & 15, head = l >> 2;
    int n = blockIdx.x * 16 + ((t >> 6) << 2) + g;
    bool valid = (n < N);
    int nn = valid ? n : 0;
    int start = rowptr[nn], end = rowptr[nn + 1];
    float adn = adst1[(nn << 2) + head];
    const char* hb = (const char*)h1h;
    const char* ab = (const char*)asrc1;
    int hoff = l << 4;
    int aoff = head << 2;
    float acc[8];
    #pragma unroll
    for (int j = 0; j < 8; j++) acc[j] = 0.f;
    float s0 = 0.f, s1 = 0.f, s2 = 0.f, s3 = 0.f;
    int i = start;
    for (; i + 7 < end; i += 8){
        int sv[8];
        #pragma unroll
        for (int q = 0; q < 8; q++) sv[q] = csr_src[i + q];
        half8 hv[8];
        #pragma unroll
        for (int q = 0; q < 8; q++)
            hv[q] = *(const half8*)(hb + ((size_t)sv[q] << 8) + hoff);
        float wv[8];
        #pragma unroll
        for (int q = 0; q < 8; q++){
            float e = *(const float*)(ab + ((size_t)sv[q] << 4) + aoff) + adn;
            e = fmaxf(e, NEG_SLOPE * e);
            wv[q] = __expf(e);
        }
        s0 += wv[0] + wv[4]; s1 += wv[1] + wv[5];
        s2 += wv[2] + wv[6]; s3 += wv[3] + wv[7];
        #pragma unroll
        for (int q = 0; q < 8; q++){
            #pragma unroll
            for (int j = 0; j < 8; j++)
                acc[j] = fmaf((float)hv[q][j], wv[q], acc[j]);   // v_fma_mix_f32
        }
    }
    for (; i < end; i++){
        int sa = csr_src[i];
        float e = *(const float*)(ab + ((size_t)sa << 4) + aoff) + adn;
        e = fmaxf(e, NEG_SLOPE * e);
        float wa = __expf(e);
        half8 ha = *(const half8*)(hb + ((size_t)sa << 8) + hoff);
        s0 += wa;
        #pragma unroll
        for (int j = 0; j < 8; j++)
            acc[j] = fmaf((float)ha[j], wa, acc[j]);
    }
    if (valid){
        float ssum = (s0 + s1) + (s2 + s3);
        float inv = 1.f / (ssum + EPSV);
        float o[8];
        #pragma unroll
        for (int j = 0; j < 8; j++){
            float v = acc[j] * inv + b1[l * 8 + j];
            o[j] = (v > 0.f) ? v : expm1f(v);   // ELU fused
        }
        float4 o0 = {o[0], o[1], o[2], o[3]};
        float4 o1 = {o[4], o[5], o[6], o[7]};
        *(float4*)&x2[((size_t)n << 7) + (l << 3)]     = o0;
        *(float4*)&x2[((size_t)n << 7) + (l << 3) + 4] = o1;
    }
}

// ---------------- GEMM2: 64-node tile, 48 KB LDS (3 blocks/CU), 2-node blocking ----------

__launch_bounds__(256)
__global__ void k_gemm2(const float* __restrict__ x2, const float* __restrict__ W2,
                        const float* __restrict__ a_src, const float* __restrict__ a_dst,
                        _Float16* __restrict__ h2h, float* __restrict__ asrc2,
                        float* __restrict__ adst2, int N){
    __shared__ float Wl[128 * 32];    // 16 KB
    __shared__ float xl[64 * 128];    // 32 KB
    int t = threadIdx.x;
    int cg = t & 7, ns = t >> 3;      // ns in 0..31
    for (int idx = t; idx < 1024; idx += 256)
        *(float4*)&Wl[idx * 4] = *(const float4*)&W2[idx * 4];
    int n0 = blockIdx.x * 64;
    for (int idx = t; idx < 2048; idx += 256){
        int row = idx >> 5, k4 = idx & 31;
        float4 v = {0.f, 0.f, 0.f, 0.f};
        if (n0 + row < N) v = *(const float4*)&x2[(size_t)(n0 + row) * 128 + k4 * 4];
        *(float4*)&xl[row * 128 + k4 * 4] = v;
    }
    __syncthreads();
    float4 acc0 = {0,0,0,0}, acc1 = {0,0,0,0};
    #pragma unroll 2
    for (int k = 0; k < 128; k += 4){
        float4 xv0 = *(float4*)&xl[(ns      ) * 128 + k];
        float4 xv1 = *(float4*)&xl[(ns + 32) * 128 + k];
        #pragma unroll
        for (int kk = 0; kk < 4; kk++){
            float4 w = *(float4*)&Wl[(k + kk) * 32 + cg * 4];
            float x0 = ((float*)&xv0)[kk];
            float x1 = ((float*)&xv1)[kk];
            acc0.x = fmaf(x0, w.x, acc0.x); acc0.y = fmaf(x0, w.y, acc0.y);
            acc0.z = fmaf(x0, w.z, acc0.z); acc0.w = fmaf(x0, w.w, acc0.w);
            acc1.x = fmaf(x1, w.x, acc1.x); acc1.y = fmaf(x1, w.y, acc1.y);
            acc1.z = fmaf(x1, w.z, acc1.z); acc1.w = fmaf(x1, w.w, acc1.w);
        }
    }
    float4 a4s = *(const float4*)&a_src[cg * 4];
    float4 a4d = *(const float4*)&a_dst[cg * 4];
    float4 accs[2] = {acc0, acc1};
    #pragma unroll
    for (int j = 0; j < 2; j++){
        int n = n0 + ns + 32 * j;
        if (n >= N) continue;
        float4 a = accs[j];
        half4 hv;
        hv.x = (_Float16)a.x; hv.y = (_Float16)a.y;
        hv.z = (_Float16)a.z; hv.w = (_Float16)a.w;
        *(half4*)&h2h[((size_t)n << 5) + (cg << 2)] = hv;
        float vs = a.x * a4s.x + a.y * a4s.y + a.z * a4s.z + a.w * a4s.w;
        float vd = a.x * a4d.x + a.y * a4d.y + a.z * a4d.z + a.w * a4d.w;
        #pragma unroll
        for (int m = 1; m <= 4; m <<= 1){
            vs += __shfl_xor(vs, m, 64);
            vd += __shfl_xor(vd, m, 64);
        }
        if (cg == 0){ asrc2[n] = vs; adst2[n] = vd; }
    }
}

// ---------------- Aggregation L2: GROUP-PER-NODE, unroll-8, fma_mix ---------------------
// 8 lanes own one node. h2h (3.2MB) and asrc2 (200KB) are L2-resident -> latency-bound,
// fixed by 8 deep independent chains.

__launch_bounds__(256)
__global__ void k_agg2(const int* __restrict__ rowptr, const int* __restrict__ csr_src,
                       const float* __restrict__ asrc2, const float* __restrict__ adst2,
                       const _Float16* __restrict__ h2h,
                       const float* __restrict__ b2, float* __restrict__ out, int N){
    int t = threadIdx.x;
    int lane = t & 63;
    int g = lane >> 3, l = lane & 7;
    int n = blockIdx.x * 32 + ((t >> 6) << 3) + g;
    bool valid = (n < N);
    int nn = valid ? n : 0;
    int start = rowptr[nn], end = rowptr[nn + 1];
    float adn = adst2[nn];
    const char* hb = (const char*)h2h;
    const char* ab = (const char*)asrc2;
    int hoff = l << 3;
    float acc[4];
    #pragma unroll
    for (int j = 0; j < 4; j++) acc[j] = 0.f;
    float s0 = 0.f, s1 = 0.f, s2 = 0.f, s3 = 0.f;
    int i = start;
    for (; i + 7 < end; i += 8){
        int sv[8];
        #pragma unroll
        for (int q = 0; q < 8; q++) sv[q] = csr_src[i + q];
        half4 hv[8];
        #pragma unroll
        for (int q = 0; q < 8; q++)
            hv[q] = *(const half4*)(hb + ((size_t)sv[q] << 6) + hoff);
        float wv[8];
        #pragma unroll
        for (int q = 0; q < 8; q++){
            float e = *(const float*)(ab + ((size_t)sv[q] << 2)) + adn;
            e = fmaxf(e, NEG_SLOPE * e);
            wv[q] = __expf(e);
        }
        s0 += wv[0] + wv[4]; s1 += wv[1] + wv[5];
        s2 += wv[2] + wv[6]; s3 += wv[3] + wv[7];
        #pragma unroll
        for (int q = 0; q < 8; q++){
            acc[0] = fmaf((float)hv[q].x, wv[q], acc[0]);
            acc[1] = fmaf((float)hv[q].y, wv[q], acc[1]);
            acc[2] = fmaf((float)hv[q].z, wv[q], acc[2]);
            acc[3] = fmaf((float)hv[q].w, wv[q], acc[3]);
        }
    }
    for (; i < end; i++){
        int sa = csr_src[i];
        float e = *(const float*)(ab + ((size_t)sa << 2)) + adn;
        e = fmaxf(e, NEG_SLOPE * e);
        float wa = __expf(e);
        half4 ha = *(const half4*)(hb + ((size_t)sa << 6) + hoff);
        s0 += wa;
        acc[0] = fmaf((float)ha.x, wa, acc[0]);
        acc[1] = fmaf((float)ha.y, wa, acc[1]);
        acc[2] = fmaf((float)ha.z, wa, acc[2]);
        acc[3] = fmaf((float)ha.w, wa, acc[3]);
    }
    if (valid){
        float ssum = (s0 + s1) + (s2 + s3);
        float inv = 1.f / (ssum + EPSV);
        const float4 b4 = *(const float4*)&b2[l * 4];
        float4 o;
        o.x = acc[0] * inv + b4.x; o.y = acc[1] * inv + b4.y;
        o.z = acc[2] * inv + b4.z; o.w = acc[3] * inv + b4.w;
        *(float4*)&out[((size_t)n << 5) + (l << 2)] = o;
    }
}

// ---------------- launch ----------------

extern "C" void kernel_launch(void* const* d_in, const int* in_sizes, int n_in,
                              void* d_out, int out_size, void* d_ws, size_t ws_size,
                              hipStream_t stream){
    const float* x      = (const float*)d_in[0];
    const int*   ei     = (const int*)  d_in[1];
    const float* W1     = (const float*)d_in[2];
    const float* a_src1 = (const float*)d_in[3];
    const float* a_dst1 = (const float*)d_in[4];
    const float* b1     = (const float*)d_in[5];
    const float* W2     = (const float*)d_in[6];
    const float* a_src2 = (const float*)d_in[7];
    const float* a_dst2 = (const float*)d_in[8];
    const float* b2     = (const float*)d_in[9];
    float* out = (float*)d_out;

    int N  = in_sizes[0] / 128;
    int E  = in_sizes[1] / 2;
    int ET = E + N;
    int nScanBlk = (N + 1023) / 1024;
    int G  = (ET + 255) / 256;
    int GH = (ET + 1023) / 1024;
    int nGemmBlk = (N + 63) / 64;

    char* ws = (char*)d_ws;
    size_t off = 0;
    auto alloc = [&](size_t bytes) -> char* {
        char* p = ws + off;
        off += (bytes + 255) & ~(size_t)255;
        return p;
    };
    int*            degp    = (int*)           alloc((size_t)NPART * N * 4);
    int*            rowptr  = (int*)           alloc((size_t)(N + 1) * 4);
    int*            bsum    = (int*)           alloc((size_t)nScanBlk * 4);
    int*            cursor  = (int*)           alloc((size_t)NPART * N * 4);
    int*            csr_src = (int*)           alloc((size_t)ET * 4);
    _Float16*       h1h     = (_Float16*)      alloc((size_t)N * 128 * 2);
    float*          x2      = (float*)         alloc((size_t)N * 128 * 4);
    float*          asrc1   = (float*)         alloc((size_t)N * 4 * 4);
    float*          adst1   = (float*)         alloc((size_t)N * 4 * 4);
    _Float16*       h2h     = (_Float16*)      alloc((size_t)N * 32 * 2);
    float*          asrc2   = (float*)         alloc((size_t)N * 4);
    float*          adst2   = (float*)         alloc((size_t)N * 4);
    _Float16*       W1f     = (_Float16*)      alloc((size_t)32 * 512 * 2);   // 32 KB
    _Float16*       Uf      = (_Float16*)      alloc((size_t)4 * 512 * 2);    // 4 KB

    hipMemsetAsync(degp, 0, (size_t)NPART * N * 4, stream);
    hipLaunchKernelGGL(k_pack,      dim3(33), dim3(256), 0, stream, W1, a_src1, a_dst1, W1f, Uf);
    hipLaunchKernelGGL(k_hist,      dim3(GH), dim3(256), 0, stream, ei, E, ET, N, (unsigned int*)degp);
    hipLaunchKernelGGL(k_gemm1,     dim3(nGemmBlk), dim3(256), 0, stream, x, W1f, Uf, h1h, asrc1, adst1, N);
    hipLaunchKernelGGL(k_scan_blk,  dim3(nScanBlk), dim3(256), 0, stream, degp, N, rowptr, bsum);
    hipLaunchKernelGGL(k_finalize,  dim3((N + 255) / 256), dim3(256), 0, stream, bsum, degp, N, ET, rowptr, cursor);
    hipLaunchKernelGGL(k_scatter_c, dim3(G), dim3(256), 0, stream, ei, E, ET, N, cursor, csr_src);
    hipLaunchKernelGGL(k_agg1,      dim3((N + 15) / 16), dim3(256), 0, stream, rowptr, csr_src, asrc1, adst1, h1h, b1, x2, N);
    hipLaunchKernelGGL(k_gemm2,     dim3((N + 63) / 64), dim3(256), 0, stream, x2, W2, a_src2, a_dst2, h2h, asrc2, adst2, N);
    hipLaunchKernelGGL(k_agg2,      dim3((N + 31) / 32), dim3(256), 0, stream, rowptr, csr_src, asrc2, adst2, h2h, b2, out, N);
}

// Round 11
// 315.418 us; speedup vs baseline: 1.3326x; 1.3326x over previous
//
#include <hip/hip_runtime.h>
#include <math.h>

#define NEG_SLOPE 0.2f
#define EPSV 1e-16f
#define NPART 8

typedef _Float16 half4 __attribute__((ext_vector_type(4)));
typedef _Float16 half8 __attribute__((ext_vector_type(8)));
typedef float f32x4 __attribute__((ext_vector_type(4)));

// ---------------- CSR build ----------------

// block scan over 1024-node chunks; deg computed inline from degp; bsum = raw chunk sum
__global__ void k_scan_blk(const int* __restrict__ degp, int N,
                           int* __restrict__ rowptr, int* __restrict__ bsum){
    int b = blockIdx.x, t = threadIdx.x;
    int base = b * 1024 + t * 4;
    int v[4];
    #pragma unroll
    for (int j = 0; j < 4; j++){
        int n = base + j, s = 0;
        if (n < N){
            #pragma unroll
            for (int p = 0; p < NPART; p++) s += degp[p * N + n];
        }
        v[j] = s;
    }
    int s = v[0] + v[1] + v[2] + v[3];
    int lane = t & 63, wid = t >> 6;
    int x = s;
    #pragma unroll
    for (int off = 1; off < 64; off <<= 1){
        int y = __shfl_up(x, off, 64);
        if (lane >= off) x += y;
    }
    __shared__ int ws[4];
    if (lane == 63) ws[wid] = x;
    __syncthreads();
    int woff = 0;
    for (int w = 0; w < wid; w++) woff += ws[w];
    int run = woff + x - s;
    #pragma unroll
    for (int j = 0; j < 4; j++){
        if (base + j < N) rowptr[base + j] = run;
        run += v[j];
    }
    if (t == 255) bsum[b] = woff + x;
}

// rowptr += prefix(bsum); poff[p][n] = rowptr[n] + prefix_p(degp[.][n])
__global__ void k_finalize(const int* __restrict__ bsum, const int* __restrict__ degp,
                           int N, int ET,
                           int* __restrict__ rowptr, int* __restrict__ poff){
    int b = blockIdx.x, t = threadIdx.x;
    int n = b * 256 + t;
    int chunk = (b * 256) >> 10;           // wave-uniform
    int off = 0;
    for (int c = 0; c < chunk; c++) off += bsum[c];
    if (n < N){
        int r = rowptr[n] + off;
        rowptr[n] = r;
        int run = r;
        #pragma unroll
        for (int p = 0; p < NPART; p++){
            poff[p * N + n] = run;
            run += degp[p * N + n];
        }
    }
    if (n == 0) rowptr[N] = ET;
}

// atomic-free scatter (measured ~15us): partition packed in rank[15:13]
__launch_bounds__(256)
__global__ void k_scatter2(const int* __restrict__ ei, int E, int ET, int N,
                           const int* __restrict__ poff,
                           const unsigned short* __restrict__ rank,
                           int* __restrict__ csr_src){
    int i = blockIdx.x * 256 + threadIdx.x;
    if (i >= ET) return;
    int s, d;
    if (i < E){ s = ei[i]; d = ei[E + i]; } else { s = i - E; d = s; }
    int pr = rank[i];
    int p = pr >> 13, r = pr & 0x1FFF;
    csr_src[poff[p * N + d] + r] = s;
}

// ---------------- Pack: W1 -> fp16 MFMA B-fragments; U = W1 @ [a_src | a_dst] ----------

__global__ void k_pack(const float* __restrict__ W1, const float* __restrict__ a_src,
                       const float* __restrict__ a_dst,
                       _Float16* __restrict__ W1f, _Float16* __restrict__ Uf){
    int b = blockIdx.x, t = threadIdx.x;
    if (b < 32){
        #pragma unroll
        for (int i = 0; i < 2; i++){
            int idx = t + 256 * i;                 // 0..511
            int jj = idx & 7, ln = idx >> 3;       // ln 0..63
            int kt = b & 3, ct = b >> 2;
            int k = kt * 32 + (ln >> 4) * 8 + jj;
            int col = ct * 16 + (ln & 15);
            W1f[b * 512 + idx] = (_Float16)W1[k * 128 + col];
        }
        return;
    }
    // b == 32: compute U[128][8] then pack Uf
    __shared__ float U[128 * 8];
    if (t < 128){
        #pragma unroll
        for (int h = 0; h < 4; h++){
            float s = 0.f, d = 0.f;
            for (int cc = 0; cc < 32; cc++){
                float w = W1[t * 128 + h * 32 + cc];
                s += w * a_src[h * 32 + cc];
                d += w * a_dst[h * 32 + cc];
            }
            U[t * 8 + h]     = s;
            U[t * 8 + h + 4] = d;
        }
    }
    __syncthreads();
    for (int idx = t; idx < 4 * 64 * 8; idx += 256){
        int jj = idx & 7, ln = (idx >> 3) & 63, kt = idx >> 9;
        int k = kt * 32 + (ln >> 4) * 8 + jj;
        int col = ln & 15;
        Uf[idx] = (_Float16)(col < 8 ? U[k * 8 + col] : 0.f);
    }
}

// ---------------- Fused: hist_rank (blocks [0,GH)) + MFMA GEMM1 (rest) ------------------
// ROUND-6 FORM VERBATIM (measured 67.6-71.1us): hist first, 4096 edges/block, 16/thread
// phase-split; partition = physical XCD, workgroup-scope atomic -> per-XCD L2 RMW.
// GEMM: 64 nodes/block, 4 waves x 16 rows, 36 MFMA/wave, no LDS, no barriers.

__launch_bounds__(256)
__global__ void k_gemm1_hist(const float* __restrict__ x, const _Float16* __restrict__ W1f,
                             const _Float16* __restrict__ Uf,
                             _Float16* __restrict__ h1h, float* __restrict__ asrc1,
                             float* __restrict__ adst1, int N, int GH,
                             const int* __restrict__ ei, int E, int ET,
                             unsigned int* __restrict__ degp, unsigned short* __restrict__ rank){
    int t = threadIdx.x;
    if ((int)blockIdx.x < GH){
        int p = __builtin_amdgcn_s_getreg((3 << 11) | 20) & 7;   // HW_REG_XCC_ID
        int base = blockIdx.x * 4096 + t;
        int d[16];
        #pragma unroll
        for (int j = 0; j < 16; j++){
            int i = base + j * 256;
            d[j] = (i < ET) ? ((i < E) ? ei[E + i] : (i - E)) : 0;
        }
        unsigned r[16];
        #pragma unroll
        for (int j = 0; j < 16; j++){
            int i = base + j * 256;
            r[j] = 0;
            if (i < ET)
                r[j] = __hip_atomic_fetch_add(&degp[(size_t)p * N + d[j]], 1u,
                           __ATOMIC_RELAXED, __HIP_MEMORY_SCOPE_WORKGROUP);
        }
        #pragma unroll
        for (int j = 0; j < 16; j++){
            int i = base + j * 256;
            if (i < ET) rank[i] = (unsigned short)((p << 13) | r[j]);
        }
        return;
    }
    // ---- gemm1 MFMA part ----
    int gb = blockIdx.x - GH;
    int w = t >> 6, lane = t & 63;
    int arow = gb * 64 + w * 16 + (lane & 15);             // A-fragment row
    bool arow_ok = (arow < N);
    const float4* xr = (const float4*)&x[(size_t)(arow_ok ? arow : 0) << 7];
    const half8* Wf = (const half8*)W1f;
    const half8* Uv = (const half8*)Uf;

    f32x4 acc[8];
    #pragma unroll
    for (int c = 0; c < 8; c++) acc[c] = (f32x4)0.f;
    f32x4 accA = (f32x4)0.f;

    #pragma unroll
    for (int kt = 0; kt < 4; kt++){
        half8 af;
        if (arow_ok){
            float4 p0 = xr[kt * 8 + (lane >> 4) * 2];
            float4 p1 = xr[kt * 8 + (lane >> 4) * 2 + 1];
            af[0] = (_Float16)p0.x; af[1] = (_Float16)p0.y;
            af[2] = (_Float16)p0.z; af[3] = (_Float16)p0.w;
            af[4] = (_Float16)p1.x; af[5] = (_Float16)p1.y;
            af[6] = (_Float16)p1.z; af[7] = (_Float16)p1.w;
        } else {
            af[0] = (_Float16)0.f; af[1] = (_Float16)0.f;
            af[2] = (_Float16)0.f; af[3] = (_Float16)0.f;
            af[4] = (_Float16)0.f; af[5] = (_Float16)0.f;
            af[6] = (_Float16)0.f; af[7] = (_Float16)0.f;
        }
        #pragma unroll
        for (int ct = 0; ct < 8; ct++){
            half8 bf = Wf[(ct * 4 + kt) * 64 + lane];
            acc[ct] = __builtin_amdgcn_mfma_f32_16x16x32_f16(af, bf, acc[ct], 0, 0, 0);
        }
        half8 uf = Uv[kt * 64 + lane];
        accA = __builtin_amdgcn_mfma_f32_16x16x32_f16(af, uf, accA, 0, 0, 0);
    }

    // epilogue: lane l, reg r -> row=(l>>4)*4+r, col=l&15
    int g = lane >> 4, j = lane & 15;
    int rowbase = gb * 64 + w * 16 + g * 4;
    #pragma unroll
    for (int r = 0; r < 4; r++){
        int n = rowbase + r;
        if (n >= N) continue;
        _Float16* hrow = &h1h[(size_t)n << 7];
        #pragma unroll
        for (int ct = 0; ct < 8; ct++)
            hrow[ct * 16 + j] = (_Float16)acc[ct][r];
        float av = accA[r];
        if (j < 4)            asrc1[n * 4 + j]       = av;
        else if (j < 8)       adst1[n * 4 + (j - 4)] = av;
    }
}

// ---------------- Aggregation L1: GROUP-PER-NODE, unroll-8, fma_mix accumulate ----------

__launch_bounds__(256)
__global__ void k_agg1(const int* __restrict__ rowptr, const int* __restrict__ csr_src,
                       const float* __restrict__ asrc1, const float* __restrict__ adst1,
                       const _Float16* __restrict__ h1h,
                       const float* __restrict__ b1, float* __restrict__ x2, int N){
    int t = threadIdx.x;
    int lane = t & 63;
    int g = lane >> 4, l = lane & 15, head = l >> 2;
    int n = blockIdx.x * 16 + ((t >> 6) << 2) + g;
    bool valid = (n < N);
    int nn = valid ? n : 0;
    int start = rowptr[nn], end = rowptr[nn + 1];
    float adn = adst1[(nn << 2) + head];
    const char* hb = (const char*)h1h;
    const char* ab = (const char*)asrc1;
    int hoff = l << 4;
    int aoff = head << 2;
    float acc[8];
    #pragma unroll
    for (int j = 0; j < 8; j++) acc[j] = 0.f;
    float s0 = 0.f, s1 = 0.f, s2 = 0.f, s3 = 0.f;
    int i = start;
    for (; i + 7 < end; i += 8){
        int sv[8];
        #pragma unroll
        for (int q = 0; q < 8; q++) sv[q] = csr_src[i + q];
        half8 hv[8];
        #pragma unroll
        for (int q = 0; q < 8; q++)
            hv[q] = *(const half8*)(hb + ((size_t)sv[q] << 8) + hoff);
        float wv[8];
        #pragma unroll
        for (int q = 0; q < 8; q++){
            float e = *(const float*)(ab + ((size_t)sv[q] << 4) + aoff) + adn;
            e = fmaxf(e, NEG_SLOPE * e);
            wv[q] = __expf(e);
        }
        s0 += wv[0] + wv[4]; s1 += wv[1] + wv[5];
        s2 += wv[2] + wv[6]; s3 += wv[3] + wv[7];
        #pragma unroll
        for (int q = 0; q < 8; q++){
            #pragma unroll
            for (int j = 0; j < 8; j++)
                acc[j] = fmaf((float)hv[q][j], wv[q], acc[j]);   // v_fma_mix_f32
        }
    }
    for (; i < end; i++){
        int sa = csr_src[i];
        float e = *(const float*)(ab + ((size_t)sa << 4) + aoff) + adn;
        e = fmaxf(e, NEG_SLOPE * e);
        float wa = __expf(e);
        half8 ha = *(const half8*)(hb + ((size_t)sa << 8) + hoff);
        s0 += wa;
        #pragma unroll
        for (int j = 0; j < 8; j++)
            acc[j] = fmaf((float)ha[j], wa, acc[j]);
    }
    if (valid){
        float ssum = (s0 + s1) + (s2 + s3);
        float inv = 1.f / (ssum + EPSV);
        float o[8];
        #pragma unroll
        for (int j = 0; j < 8; j++){
            float v = acc[j] * inv + b1[l * 8 + j];
            o[j] = (v > 0.f) ? v : expm1f(v);   // ELU fused
        }
        float4 o0 = {o[0], o[1], o[2], o[3]};
        float4 o1 = {o[4], o[5], o[6], o[7]};
        *(float4*)&x2[((size_t)n << 7) + (l << 3)]     = o0;
        *(float4*)&x2[((size_t)n << 7) + (l << 3) + 4] = o1;
    }
}

// ---------------- GEMM2: 64-node tile, 48 KB LDS (3 blocks/CU), 2-node blocking ----------

__launch_bounds__(256)
__global__ void k_gemm2(const float* __restrict__ x2, const float* __restrict__ W2,
                        const float* __restrict__ a_src, const float* __restrict__ a_dst,
                        _Float16* __restrict__ h2h, float* __restrict__ asrc2,
                        float* __restrict__ adst2, int N){
    __shared__ float Wl[128 * 32];    // 16 KB
    __shared__ float xl[64 * 128];    // 32 KB
    int t = threadIdx.x;
    int cg = t & 7, ns = t >> 3;      // ns in 0..31
    for (int idx = t; idx < 1024; idx += 256)
        *(float4*)&Wl[idx * 4] = *(const float4*)&W2[idx * 4];
    int n0 = blockIdx.x * 64;
    for (int idx = t; idx < 2048; idx += 256){
        int row = idx >> 5, k4 = idx & 31;
        float4 v = {0.f, 0.f, 0.f, 0.f};
        if (n0 + row < N) v = *(const float4*)&x2[(size_t)(n0 + row) * 128 + k4 * 4];
        *(float4*)&xl[row * 128 + k4 * 4] = v;
    }
    __syncthreads();
    float4 acc0 = {0,0,0,0}, acc1 = {0,0,0,0};
    #pragma unroll 2
    for (int k = 0; k < 128; k += 4){
        float4 xv0 = *(float4*)&xl[(ns      ) * 128 + k];
        float4 xv1 = *(float4*)&xl[(ns + 32) * 128 + k];
        #pragma unroll
        for (int kk = 0; kk < 4; kk++){
            float4 w = *(float4*)&Wl[(k + kk) * 32 + cg * 4];
            float x0 = ((float*)&xv0)[kk];
            float x1 = ((float*)&xv1)[kk];
            acc0.x = fmaf(x0, w.x, acc0.x); acc0.y = fmaf(x0, w.y, acc0.y);
            acc0.z = fmaf(x0, w.z, acc0.z); acc0.w = fmaf(x0, w.w, acc0.w);
            acc1.x = fmaf(x1, w.x, acc1.x); acc1.y = fmaf(x1, w.y, acc1.y);
            acc1.z = fmaf(x1, w.z, acc1.z); acc1.w = fmaf(x1, w.w, acc1.w);
        }
    }
    float4 a4s = *(const float4*)&a_src[cg * 4];
    float4 a4d = *(const float4*)&a_dst[cg * 4];
    float4 accs[2] = {acc0, acc1};
    #pragma unroll
    for (int j = 0; j < 2; j++){
        int n = n0 + ns + 32 * j;
        if (n >= N) continue;
        float4 a = accs[j];
        half4 hv;
        hv.x = (_Float16)a.x; hv.y = (_Float16)a.y;
        hv.z = (_Float16)a.z; hv.w = (_Float16)a.w;
        *(half4*)&h2h[((size_t)n << 5) + (cg << 2)] = hv;
        float vs = a.x * a4s.x + a.y * a4s.y + a.z * a4s.z + a.w * a4s.w;
        float vd = a.x * a4d.x + a.y * a4d.y + a.z * a4d.z + a.w * a4d.w;
        #pragma unroll
        for (int m = 1; m <= 4; m <<= 1){
            vs += __shfl_xor(vs, m, 64);
            vd += __shfl_xor(vd, m, 64);
        }
        if (cg == 0){ asrc2[n] = vs; adst2[n] = vd; }
    }
}

// ---------------- Aggregation L2: GROUP-PER-NODE, unroll-8, fma_mix ---------------------

__launch_bounds__(256)
__global__ void k_agg2(const int* __restrict__ rowptr, const int* __restrict__ csr_src,
                       const float* __restrict__ asrc2, const float* __restrict__ adst2,
                       const _Float16* __restrict__ h2h,
                       const float* __restrict__ b2, float* __restrict__ out, int N){
    int t = threadIdx.x;
    int lane = t & 63;
    int g = lane >> 3, l = lane & 7;
    int n = blockIdx.x * 32 + ((t >> 6) << 3) + g;
    bool valid = (n < N);
    int nn = valid ? n : 0;
    int start = rowptr[nn], end = rowptr[nn + 1];
    float adn = adst2[nn];
    const char* hb = (const char*)h2h;
    const char* ab = (const char*)asrc2;
    int hoff = l << 3;
    float acc[4];
    #pragma unroll
    for (int j = 0; j < 4; j++) acc[j] = 0.f;
    float s0 = 0.f, s1 = 0.f, s2 = 0.f, s3 = 0.f;
    int i = start;
    for (; i + 7 < end; i += 8){
        int sv[8];
        #pragma unroll
        for (int q = 0; q < 8; q++) sv[q] = csr_src[i + q];
        half4 hv[8];
        #pragma unroll
        for (int q = 0; q < 8; q++)
            hv[q] = *(const half4*)(hb + ((size_t)sv[q] << 6) + hoff);
        float wv[8];
        #pragma unroll
        for (int q = 0; q < 8; q++){
            float e = *(const float*)(ab + ((size_t)sv[q] << 2)) + adn;
            e = fmaxf(e, NEG_SLOPE * e);
            wv[q] = __expf(e);
        }
        s0 += wv[0] + wv[4]; s1 += wv[1] + wv[5];
        s2 += wv[2] + wv[6]; s3 += wv[3] + wv[7];
        #pragma unroll
        for (int q = 0; q < 8; q++){
            acc[0] = fmaf((float)hv[q].x, wv[q], acc[0]);
            acc[1] = fmaf((float)hv[q].y, wv[q], acc[1]);
            acc[2] = fmaf((float)hv[q].z, wv[q], acc[2]);
            acc[3] = fmaf((float)hv[q].w, wv[q], acc[3]);
        }
    }
    for (; i < end; i++){
        int sa = csr_src[i];
        float e = *(const float*)(ab + ((size_t)sa << 2)) + adn;
        e = fmaxf(e, NEG_SLOPE * e);
        float wa = __expf(e);
        half4 ha = *(const half4*)(hb + ((size_t)sa << 6) + hoff);
        s0 += wa;
        acc[0] = fmaf((float)ha.x, wa, acc[0]);
        acc[1] = fmaf((float)ha.y, wa, acc[1]);
        acc[2] = fmaf((float)ha.z, wa, acc[2]);
        acc[3] = fmaf((float)ha.w, wa, acc[3]);
    }
    if (valid){
        float ssum = (s0 + s1) + (s2 + s3);
        float inv = 1.f / (ssum + EPSV);
        const float4 b4 = *(const float4*)&b2[l * 4];
        float4 o;
        o.x = acc[0] * inv + b4.x; o.y = acc[1] * inv + b4.y;
        o.z = acc[2] * inv + b4.z; o.w = acc[3] * inv + b4.w;
        *(float4*)&out[((size_t)n << 5) + (l << 2)] = o;
    }
}

// ---------------- launch ----------------

extern "C" void kernel_launch(void* const* d_in, const int* in_sizes, int n_in,
                              void* d_out, int out_size, void* d_ws, size_t ws_size,
                              hipStream_t stream){
    const float* x      = (const float*)d_in[0];
    const int*   ei     = (const int*)  d_in[1];
    const float* W1     = (const float*)d_in[2];
    const float* a_src1 = (const float*)d_in[3];
    const float* a_dst1 = (const float*)d_in[4];
    const float* b1     = (const float*)d_in[5];
    const float* W2     = (const float*)d_in[6];
    const float* a_src2 = (const float*)d_in[7];
    const float* a_dst2 = (const float*)d_in[8];
    const float* b2     = (const float*)d_in[9];
    float* out = (float*)d_out;

    int N  = in_sizes[0] / 128;
    int E  = in_sizes[1] / 2;
    int ET = E + N;
    int nScanBlk = (N + 1023) / 1024;
    int G  = (ET + 255) / 256;
    int GH = (ET + 4095) / 4096;
    int nGemmBlk = (N + 63) / 64;

    char* ws = (char*)d_ws;
    size_t off = 0;
    auto alloc = [&](size_t bytes) -> char* {
        char* p = ws + off;
        off += (bytes + 255) & ~(size_t)255;
        return p;
    };
    int*            degp    = (int*)           alloc((size_t)NPART * N * 4);
    int*            rowptr  = (int*)           alloc((size_t)(N + 1) * 4);
    int*            bsum    = (int*)           alloc((size_t)nScanBlk * 4);
    unsigned short* rank    = (unsigned short*)alloc((size_t)ET * 2);
    int*            poff    = (int*)           alloc((size_t)NPART * N * 4);
    int*            csr_src = (int*)           alloc((size_t)ET * 4);
    _Float16*       h1h     = (_Float16*)      alloc((size_t)N * 128 * 2);
    float*          x2      = (float*)         alloc((size_t)N * 128 * 4);
    float*          asrc1   = (float*)         alloc((size_t)N * 4 * 4);
    float*          adst1   = (float*)         alloc((size_t)N * 4 * 4);
    _Float16*       h2h     = (_Float16*)      alloc((size_t)N * 32 * 2);
    float*          asrc2   = (float*)         alloc((size_t)N * 4);
    float*          adst2   = (float*)         alloc((size_t)N * 4);
    _Float16*       W1f     = (_Float16*)      alloc((size_t)32 * 512 * 2);   // 32 KB
    _Float16*       Uf      = (_Float16*)      alloc((size_t)4 * 512 * 2);    // 4 KB

    hipMemsetAsync(degp, 0, (size_t)NPART * N * 4, stream);
    hipLaunchKernelGGL(k_pack,       dim3(33), dim3(256), 0, stream, W1, a_src1, a_dst1, W1f, Uf);
    hipLaunchKernelGGL(k_gemm1_hist, dim3(GH + nGemmBlk), dim3(256), 0, stream,
                       x, W1f, Uf, h1h, asrc1, adst1, N, GH,
                       ei, E, ET, (unsigned int*)degp, rank);
    hipLaunchKernelGGL(k_scan_blk,  dim3(nScanBlk), dim3(256), 0, stream, degp, N, rowptr, bsum);
    hipLaunchKernelGGL(k_finalize,  dim3((N + 255) / 256), dim3(256), 0, stream, bsum, degp, N, ET, rowptr, poff);
    hipLaunchKernelGGL(k_scatter2,  dim3(G), dim3(256), 0, stream, ei, E, ET, N, poff, rank, csr_src);
    hipLaunchKernelGGL(k_agg1,      dim3((N + 15) / 16), dim3(256), 0, stream, rowptr, csr_src, asrc1, adst1, h1h, b1, x2, N);
    hipLaunchKernelGGL(k_gemm2,     dim3((N + 63) / 64), dim3(256), 0, stream, x2, W2, a_src2, a_dst2, h2h, asrc2, adst2, N);
    hipLaunchKernelGGL(k_agg2,      dim3((N + 31) / 32), dim3(256), 0, stream, rowptr, csr_src, asrc2, adst2, h2h, b2, out, N);
}

// Round 12
// 295.540 us; speedup vs baseline: 1.4223x; 1.0673x over previous
//
#include <hip/hip_runtime.h>
#include <math.h>

#define NEG_SLOPE 0.2f
#define EPSV 1e-16f
#define NPART 8

typedef _Float16 half4 __attribute__((ext_vector_type(4)));
typedef _Float16 half8 __attribute__((ext_vector_type(8)));
typedef float floatx2 __attribute__((ext_vector_type(2)));
typedef float f32x4 __attribute__((ext_vector_type(4)));

// ---------------- CSR build ----------------

// block scan over 1024-node chunks; deg computed inline from degp; bsum = raw chunk sum
__global__ void k_scan_blk(const int* __restrict__ degp, int N,
                           int* __restrict__ rowptr, int* __restrict__ bsum){
    int b = blockIdx.x, t = threadIdx.x;
    int base = b * 1024 + t * 4;
    int v[4];
    #pragma unroll
    for (int j = 0; j < 4; j++){
        int n = base + j, s = 0;
        if (n < N){
            #pragma unroll
            for (int p = 0; p < NPART; p++) s += degp[p * N + n];
        }
        v[j] = s;
    }
    int s = v[0] + v[1] + v[2] + v[3];
    int lane = t & 63, wid = t >> 6;
    int x = s;
    #pragma unroll
    for (int off = 1; off < 64; off <<= 1){
        int y = __shfl_up(x, off, 64);
        if (lane >= off) x += y;
    }
    __shared__ int ws[4];
    if (lane == 63) ws[wid] = x;
    __syncthreads();
    int woff = 0;
    for (int w = 0; w < wid; w++) woff += ws[w];
    int run = woff + x - s;
    #pragma unroll
    for (int j = 0; j < 4; j++){
        if (base + j < N) rowptr[base + j] = run;
        run += v[j];
    }
    if (t == 255) bsum[b] = woff + x;
}

// rowptr += prefix(bsum); poff[p][n] = rowptr[n] + prefix_p(degp[.][n])
__global__ void k_finalize(const int* __restrict__ bsum, const int* __restrict__ degp,
                           int N, int ET,
                           int* __restrict__ rowptr, int* __restrict__ poff){
    int b = blockIdx.x, t = threadIdx.x;
    int n = b * 256 + t;
    int chunk = (b * 256) >> 10;           // wave-uniform
    int off = 0;
    for (int c = 0; c < chunk; c++) off += bsum[c];
    if (n < N){
        int r = rowptr[n] + off;
        rowptr[n] = r;
        int run = r;
        #pragma unroll
        for (int p = 0; p < NPART; p++){
            poff[p * N + n] = run;
            run += degp[p * N + n];
        }
    }
    if (n == 0) rowptr[N] = ET;
}

// atomic-free scatter (measured ~15us): partition packed in rank[15:13]
__launch_bounds__(256)
__global__ void k_scatter2(const int* __restrict__ ei, int E, int ET, int N,
                           const int* __restrict__ poff,
                           const unsigned short* __restrict__ rank,
                           int* __restrict__ csr_src){
    int i = blockIdx.x * 256 + threadIdx.x;
    if (i >= ET) return;
    int s, d;
    if (i < E){ s = ei[i]; d = ei[E + i]; } else { s = i - E; d = s; }
    int pr = rank[i];
    int p = pr >> 13, r = pr & 0x1FFF;
    csr_src[poff[p * N + d] + r] = s;
}

// ---------------- Pack: W1/W2 -> fp16 MFMA B-fragments; U = W @ [a_src | a_dst] --------
// Fragment layout (16x16x32): elem (lane, j) holds k = kt*32 + (lane>>4)*8 + j,
// col = ct*16 + (lane&15). b<32: W1 tiles; b==32: U1; b in [33,41): W2 tiles; b==41: U2.

__global__ void k_pack(const float* __restrict__ W1, const float* __restrict__ a_src1,
                       const float* __restrict__ a_dst1,
                       const float* __restrict__ W2, const float* __restrict__ a_src2,
                       const float* __restrict__ a_dst2,
                       _Float16* __restrict__ W1f, _Float16* __restrict__ Uf,
                       _Float16* __restrict__ W2f, _Float16* __restrict__ U2f){
    int b = blockIdx.x, t = threadIdx.x;
    if (b < 32){
        #pragma unroll
        for (int i = 0; i < 2; i++){
            int idx = t + 256 * i;                 // 0..511
            int jj = idx & 7, ln = idx >> 3;       // ln 0..63
            int kt = b & 3, ct = b >> 2;
            int k = kt * 32 + (ln >> 4) * 8 + jj;
            int col = ct * 16 + (ln & 15);
            W1f[b * 512 + idx] = (_Float16)W1[k * 128 + col];
        }
        return;
    }
    if (b == 32){
        // U1[128][8]: cols 0-3 = W1@a_src1 heads, 4-7 = W1@a_dst1 heads
        __shared__ float U[128 * 8];
        if (t < 128){
            #pragma unroll
            for (int h = 0; h < 4; h++){
                float s = 0.f, d = 0.f;
                for (int cc = 0; cc < 32; cc++){
                    float w = W1[t * 128 + h * 32 + cc];
                    s += w * a_src1[h * 32 + cc];
                    d += w * a_dst1[h * 32 + cc];
                }
                U[t * 8 + h]     = s;
                U[t * 8 + h + 4] = d;
            }
        }
        __syncthreads();
        for (int idx = t; idx < 4 * 64 * 8; idx += 256){
            int jj = idx & 7, ln = (idx >> 3) & 63, kt = idx >> 9;
            int k = kt * 32 + (ln >> 4) * 8 + jj;
            int col = ln & 15;
            Uf[idx] = (_Float16)(col < 8 ? U[k * 8 + col] : 0.f);
        }
        return;
    }
    if (b < 41){
        // W2 tile tb: kt = tb&3, ct = tb>>2 (ct in 0..1); W2 is [128][32]
        int tb = b - 33;
        #pragma unroll
        for (int i = 0; i < 2; i++){
            int idx = t + 256 * i;
            int jj = idx & 7, ln = idx >> 3;
            int kt = tb & 3, ct = tb >> 2;
            int k = kt * 32 + (ln >> 4) * 8 + jj;
            int col = ct * 16 + (ln & 15);
            W2f[tb * 512 + idx] = (_Float16)W2[k * 32 + col];
        }
        return;
    }
    // b == 41: U2[128][2]: col0 = W2@a_src2, col1 = W2@a_dst2
    __shared__ float U2[128 * 2];
    if (t < 128){
        float s = 0.f, d = 0.f;
        for (int cc = 0; cc < 32; cc++){
            float w = W2[t * 32 + cc];
            s += w * a_src2[cc];
            d += w * a_dst2[cc];
        }
        U2[t * 2]     = s;
        U2[t * 2 + 1] = d;
    }
    __syncthreads();
    for (int idx = t; idx < 4 * 64 * 8; idx += 256){
        int jj = idx & 7, ln = (idx >> 3) & 63, kt = idx >> 9;
        int k = kt * 32 + (ln >> 4) * 8 + jj;
        int col = ln & 15;
        U2f[idx] = (_Float16)(col < 2 ? U2[k * 2 + col] : 0.f);
    }
}

// ---------------- Fused: hist_rank (blocks [0,GH)) + MFMA GEMM1 (rest) ------------------
// ROUND-6 FORM (best measured 67.6-71.1us): hist first, 4096 edges/block, 16/thread
// phase-split; partition = physical XCD, workgroup-scope atomic -> per-XCD L2 RMW.

__launch_bounds__(256)
__global__ void k_gemm1_hist(const float* __restrict__ x, const _Float16* __restrict__ W1f,
                             const _Float16* __restrict__ Uf,
                             _Float16* __restrict__ h1h, float* __restrict__ asrc1,
                             float* __restrict__ adst1, int N, int GH,
                             const int* __restrict__ ei, int E, int ET,
                             unsigned int* __restrict__ degp, unsigned short* __restrict__ rank){
    int t = threadIdx.x;
    if ((int)blockIdx.x < GH){
        int p = __builtin_amdgcn_s_getreg((3 << 11) | 20) & 7;   // HW_REG_XCC_ID
        int base = blockIdx.x * 4096 + t;
        int d[16];
        #pragma unroll
        for (int j = 0; j < 16; j++){
            int i = base + j * 256;
            d[j] = (i < ET) ? ((i < E) ? ei[E + i] : (i - E)) : 0;
        }
        unsigned r[16];
        #pragma unroll
        for (int j = 0; j < 16; j++){
            int i = base + j * 256;
            r[j] = 0;
            if (i < ET)
                r[j] = __hip_atomic_fetch_add(&degp[(size_t)p * N + d[j]], 1u,
                           __ATOMIC_RELAXED, __HIP_MEMORY_SCOPE_WORKGROUP);
        }
        #pragma unroll
        for (int j = 0; j < 16; j++){
            int i = base + j * 256;
            if (i < ET) rank[i] = (unsigned short)((p << 13) | r[j]);
        }
        return;
    }
    // ---- gemm1 MFMA part ----
    int gb = blockIdx.x - GH;
    int w = t >> 6, lane = t & 63;
    int arow = gb * 64 + w * 16 + (lane & 15);             // A-fragment row
    bool arow_ok = (arow < N);
    const float4* xr = (const float4*)&x[(size_t)(arow_ok ? arow : 0) << 7];
    const half8* Wf = (const half8*)W1f;
    const half8* Uv = (const half8*)Uf;

    f32x4 acc[8];
    #pragma unroll
    for (int c = 0; c < 8; c++) acc[c] = (f32x4)0.f;
    f32x4 accA = (f32x4)0.f;

    #pragma unroll
    for (int kt = 0; kt < 4; kt++){
        half8 af;
        if (arow_ok){
            float4 p0 = xr[kt * 8 + (lane >> 4) * 2];
            float4 p1 = xr[kt * 8 + (lane >> 4) * 2 + 1];
            af[0] = (_Float16)p0.x; af[1] = (_Float16)p0.y;
            af[2] = (_Float16)p0.z; af[3] = (_Float16)p0.w;
            af[4] = (_Float16)p1.x; af[5] = (_Float16)p1.y;
            af[6] = (_Float16)p1.z; af[7] = (_Float16)p1.w;
        } else {
            af[0] = (_Float16)0.f; af[1] = (_Float16)0.f;
            af[2] = (_Float16)0.f; af[3] = (_Float16)0.f;
            af[4] = (_Float16)0.f; af[5] = (_Float16)0.f;
            af[6] = (_Float16)0.f; af[7] = (_Float16)0.f;
        }
        #pragma unroll
        for (int ct = 0; ct < 8; ct++){
            half8 bf = Wf[(ct * 4 + kt) * 64 + lane];
            acc[ct] = __builtin_amdgcn_mfma_f32_16x16x32_f16(af, bf, acc[ct], 0, 0, 0);
        }
        half8 uf = Uv[kt * 64 + lane];
        accA = __builtin_amdgcn_mfma_f32_16x16x32_f16(af, uf, accA, 0, 0, 0);
    }

    // epilogue: lane l, reg r -> row=(l>>4)*4+r, col=l&15
    int g = lane >> 4, j = lane & 15;
    int rowbase = gb * 64 + w * 16 + g * 4;
    #pragma unroll
    for (int r = 0; r < 4; r++){
        int n = rowbase + r;
        if (n >= N) continue;
        _Float16* hrow = &h1h[(size_t)n << 7];
        #pragma unroll
        for (int ct = 0; ct < 8; ct++)
            hrow[ct * 16 + j] = (_Float16)acc[ct][r];
        float av = accA[r];
        if (j < 4)            asrc1[n * 4 + j]       = av;
        else if (j < 8)       adst1[n * 4 + (j - 4)] = av;
    }
}

// ---------------- Aggregation L1: ROUND-8 FORM (measured 65us). GROUP-PER-NODE, 16 lanes
// per node, stride-1 unroll-4 chains, pk_fma accumulate. ---------------------------------

__launch_bounds__(256)
__global__ void k_agg1(const int* __restrict__ rowptr, const int* __restrict__ csr_src,
                       const float* __restrict__ asrc1, const float* __restrict__ adst1,
                       const _Float16* __restrict__ h1h,
                       const float* __restrict__ b1, float* __restrict__ x2, int N){
    int t = threadIdx.x;
    int lane = t & 63;
    int g = lane >> 4, l = lane & 15, head = l >> 2;
    int n = blockIdx.x * 16 + ((t >> 6) << 2) + g;
    bool valid = (n < N);
    int nn = valid ? n : 0;
    int start = rowptr[nn], end = rowptr[nn + 1];
    float adn = adst1[(nn << 2) + head];
    const char* hb = (const char*)h1h;
    const char* ab = (const char*)asrc1;
    int hoff = l << 4;
    int aoff = head << 2;
    floatx2 r0[4], r1[4], r2[4], r3[4];
    #pragma unroll
    for (int j = 0; j < 4; j++){
        r0[j] = (floatx2)0.f; r1[j] = (floatx2)0.f;
        r2[j] = (floatx2)0.f; r3[j] = (floatx2)0.f;
    }
    float s0a = 0.f, s1a = 0.f, s2a = 0.f, s3a = 0.f;
    int i = start;
    for (; i + 3 < end; i += 4){
        int sa = csr_src[i];
        int sb = csr_src[i + 1];
        int sc = csr_src[i + 2];
        int sd = csr_src[i + 3];
        float ea = *(const float*)(ab + (sa << 4) + aoff) + adn;
        float eb = *(const float*)(ab + (sb << 4) + aoff) + adn;
        float ec = *(const float*)(ab + (sc << 4) + aoff) + adn;
        float ed = *(const float*)(ab + (sd << 4) + aoff) + adn;
        ea = fmaxf(ea, NEG_SLOPE * ea);
        eb = fmaxf(eb, NEG_SLOPE * eb);
        ec = fmaxf(ec, NEG_SLOPE * ec);
        ed = fmaxf(ed, NEG_SLOPE * ed);
        float wa = __expf(ea);
        float wb = __expf(eb);
        float wc = __expf(ec);
        float wd = __expf(ed);
        half8 ha = *(const half8*)(hb + (sa << 8) + hoff);
        half8 hbv = *(const half8*)(hb + (sb << 8) + hoff);
        half8 hcv = *(const half8*)(hb + (sc << 8) + hoff);
        half8 hdv = *(const half8*)(hb + (sd << 8) + hoff);
        s0a += wa; s1a += wb; s2a += wc; s3a += wd;
        floatx2 wa2 = {wa, wa}, wb2 = {wb, wb}, wc2 = {wc, wc}, wd2 = {wd, wd};
        #pragma unroll
        for (int j = 0; j < 4; j++){
            floatx2 ca = {(float)ha[2*j], (float)ha[2*j+1]};
            floatx2 cb = {(float)hbv[2*j], (float)hbv[2*j+1]};
            floatx2 cc = {(float)hcv[2*j], (float)hcv[2*j+1]};
            floatx2 cd = {(float)hdv[2*j], (float)hdv[2*j+1]};
            r0[j] = wa2 * ca + r0[j];      // v_pk_fma_f32
            r1[j] = wb2 * cb + r1[j];
            r2[j] = wc2 * cc + r2[j];
            r3[j] = wd2 * cd + r3[j];
        }
    }
    for (; i < end; i++){
        int sa = csr_src[i];
        float ea = *(const float*)(ab + (sa << 4) + aoff) + adn;
        ea = fmaxf(ea, NEG_SLOPE * ea);
        float wa = __expf(ea);
        half8 ha = *(const half8*)(hb + (sa << 8) + hoff);
        s0a += wa;
        floatx2 wa2 = {wa, wa};
        #pragma unroll
        for (int j = 0; j < 4; j++){
            floatx2 ca = {(float)ha[2*j], (float)ha[2*j+1]};
            r0[j] = wa2 * ca + r0[j];
        }
    }
    if (valid){
        float ssum = (s0a + s1a) + (s2a + s3a);
        float inv = 1.f / (ssum + EPSV);
        float o[8];
        #pragma unroll
        for (int j = 0; j < 4; j++){
            floatx2 c = (r0[j] + r1[j]) + (r2[j] + r3[j]);
            float v0 = c.x * inv + b1[l * 8 + 2*j];
            float v1 = c.y * inv + b1[l * 8 + 2*j + 1];
            o[2*j]   = (v0 > 0.f) ? v0 : expm1f(v0);   // ELU fused
            o[2*j+1] = (v1 > 0.f) ? v1 : expm1f(v1);
        }
        float4 o0 = {o[0], o[1], o[2], o[3]};
        float4 o1 = {o[4], o[5], o[6], o[7]};
        *(float4*)&x2[((size_t)n << 7) + (l << 3)]     = o0;
        *(float4*)&x2[((size_t)n << 7) + (l << 3) + 4] = o1;
    }
}

// ---------------- GEMM2: MFMA (same structure as gemm1). 64 nodes/block, 4 waves x 16
// rows, 12 MFMA/wave (2 col-tiles + fused U2 alpha), no LDS, no barriers. ----------------

__launch_bounds__(256)
__global__ void k_gemm2(const float* __restrict__ x2, const _Float16* __restrict__ W2f,
                        const _Float16* __restrict__ U2f,
                        _Float16* __restrict__ h2h, float* __restrict__ asrc2,
                        float* __restrict__ adst2, int N){
    int t = threadIdx.x;
    int w = t >> 6, lane = t & 63;
    int arow = blockIdx.x * 64 + w * 16 + (lane & 15);
    bool arow_ok = (arow < N);
    const float4* xr = (const float4*)&x2[(size_t)(arow_ok ? arow : 0) << 7];
    const half8* Wf = (const half8*)W2f;
    const half8* Uv = (const half8*)U2f;

    f32x4 acc0 = (f32x4)0.f, acc1 = (f32x4)0.f, accA = (f32x4)0.f;

    #pragma unroll
    for (int kt = 0; kt < 4; kt++){
        half8 af;
        if (arow_ok){
            float4 p0 = xr[kt * 8 + (lane >> 4) * 2];
            float4 p1 = xr[kt * 8 + (lane >> 4) * 2 + 1];
            af[0] = (_Float16)p0.x; af[1] = (_Float16)p0.y;
            af[2] = (_Float16)p0.z; af[3] = (_Float16)p0.w;
            af[4] = (_Float16)p1.x; af[5] = (_Float16)p1.y;
            af[6] = (_Float16)p1.z; af[7] = (_Float16)p1.w;
        } else {
            af[0] = (_Float16)0.f; af[1] = (_Float16)0.f;
            af[2] = (_Float16)0.f; af[3] = (_Float16)0.f;
            af[4] = (_Float16)0.f; af[5] = (_Float16)0.f;
            af[6] = (_Float16)0.f; af[7] = (_Float16)0.f;
        }
        half8 b0 = Wf[(0 * 4 + kt) * 64 + lane];
        half8 b1v = Wf[(1 * 4 + kt) * 64 + lane];
        half8 uf = Uv[kt * 64 + lane];
        acc0 = __builtin_amdgcn_mfma_f32_16x16x32_f16(af, b0, acc0, 0, 0, 0);
        acc1 = __builtin_amdgcn_mfma_f32_16x16x32_f16(af, b1v, acc1, 0, 0, 0);
        accA = __builtin_amdgcn_mfma_f32_16x16x32_f16(af, uf, accA, 0, 0, 0);
    }

    // epilogue: lane l, reg r -> row=(l>>4)*4+r, col=l&15
    int g = lane >> 4, j = lane & 15;
    int rowbase = blockIdx.x * 64 + w * 16 + g * 4;
    #pragma unroll
    for (int r = 0; r < 4; r++){
        int n = rowbase + r;
        if (n >= N) continue;
        _Float16* hrow = &h2h[(size_t)n << 5];
        hrow[j]      = (_Float16)acc0[r];
        hrow[16 + j] = (_Float16)acc1[r];
        float av = accA[r];
        if (j == 0)      asrc2[n] = av;
        else if (j == 1) adst2[n] = av;
    }
}

// ---------------- Aggregation L2: ROUND-8 FORM. GROUP-PER-NODE, 8 lanes own one node. ---

__launch_bounds__(256)
__global__ void k_agg2(const int* __restrict__ rowptr, const int* __restrict__ csr_src,
                       const float* __restrict__ asrc2, const float* __restrict__ adst2,
                       const _Float16* __restrict__ h2h,
                       const float* __restrict__ b2, float* __restrict__ out, int N){
    int t = threadIdx.x;
    int lane = t & 63;
    int g = lane >> 3, l = lane & 7;
    int n = blockIdx.x * 32 + ((t >> 6) << 3) + g;
    bool valid = (n < N);
    int nn = valid ? n : 0;
    int start = rowptr[nn], end = rowptr[nn + 1];
    float adn = adst2[nn];
    const char* hb = (const char*)h2h;
    const char* ab = (const char*)asrc2;
    int hoff = l << 3;
    floatx2 a0[2], a1[2], a2[2], a3[2];
    a0[0] = (floatx2)0.f; a0[1] = (floatx2)0.f;
    a1[0] = (floatx2)0.f; a1[1] = (floatx2)0.f;
    a2[0] = (floatx2)0.f; a2[1] = (floatx2)0.f;
    a3[0] = (floatx2)0.f; a3[1] = (floatx2)0.f;
    float s0a = 0.f, s1a = 0.f, s2a = 0.f, s3a = 0.f;
    int i = start;
    for (; i + 3 < end; i += 4){
        int sa = csr_src[i];
        int sb = csr_src[i + 1];
        int sc = csr_src[i + 2];
        int sd = csr_src[i + 3];
        float ea = *(const float*)(ab + (sa << 2)) + adn;
        float eb = *(const float*)(ab + (sb << 2)) + adn;
        float ec = *(const float*)(ab + (sc << 2)) + adn;
        float ed = *(const float*)(ab + (sd << 2)) + adn;
        ea = fmaxf(ea, NEG_SLOPE * ea);
        eb = fmaxf(eb, NEG_SLOPE * eb);
        ec = fmaxf(ec, NEG_SLOPE * ec);
        ed = fmaxf(ed, NEG_SLOPE * ed);
        float wa = __expf(ea);
        float wb = __expf(eb);
        float wc = __expf(ec);
        float wd = __expf(ed);
        half4 ha = *(const half4*)(hb + (sa << 6) + hoff);
        half4 hbv = *(const half4*)(hb + (sb << 6) + hoff);
        half4 hcv = *(const half4*)(hb + (sc << 6) + hoff);
        half4 hdv = *(const half4*)(hb + (sd << 6) + hoff);
        s0a += wa; s1a += wb; s2a += wc; s3a += wd;
        floatx2 wa2 = {wa, wa}, wb2 = {wb, wb}, wc2 = {wc, wc}, wd2 = {wd, wd};
        floatx2 ca0 = {(float)ha.x, (float)ha.y},  ca1 = {(float)ha.z, (float)ha.w};
        floatx2 cb0 = {(float)hbv.x, (float)hbv.y}, cb1 = {(float)hbv.z, (float)hbv.w};
        floatx2 cc0 = {(float)hcv.x, (float)hcv.y}, cc1 = {(float)hcv.z, (float)hcv.w};
        floatx2 cd0 = {(float)hdv.x, (float)hdv.y}, cd1 = {(float)hdv.z, (float)hdv.w};
        a0[0] = wa2 * ca0 + a0[0]; a0[1] = wa2 * ca1 + a0[1];
        a1[0] = wb2 * cb0 + a1[0]; a1[1] = wb2 * cb1 + a1[1];
        a2[0] = wc2 * cc0 + a2[0]; a2[1] = wc2 * cc1 + a2[1];
        a3[0] = wd2 * cd0 + a3[0]; a3[1] = wd2 * cd1 + a3[1];
    }
    for (; i < end; i++){
        int sa = csr_src[i];
        float ea = *(const float*)(ab + (sa << 2)) + adn;
        ea = fmaxf(ea, NEG_SLOPE * ea);
        float wa = __expf(ea);
        half4 ha = *(const half4*)(hb + (sa << 6) + hoff);
        s0a += wa;
        floatx2 wa2 = {wa, wa};
        floatx2 ca0 = {(float)ha.x, (float)ha.y}, ca1 = {(float)ha.z, (float)ha.w};
        a0[0] = wa2 * ca0 + a0[0]; a0[1] = wa2 * ca1 + a0[1];
    }
    if (valid){
        floatx2 m0 = (a0[0] + a1[0]) + (a2[0] + a3[0]);
        floatx2 m1 = (a0[1] + a1[1]) + (a2[1] + a3[1]);
        float ssum = (s0a + s1a) + (s2a + s3a);
        float inv = 1.f / (ssum + EPSV);
        const float4 b4 = *(const float4*)&b2[l * 4];
        float4 o;
        o.x = m0.x * inv + b4.x; o.y = m0.y * inv + b4.y;
        o.z = m1.x * inv + b4.z; o.w = m1.y * inv + b4.w;
        *(float4*)&out[((size_t)n << 5) + (l << 2)] = o;
    }
}

// ---------------- launch ----------------

extern "C" void kernel_launch(void* const* d_in, const int* in_sizes, int n_in,
                              void* d_out, int out_size, void* d_ws, size_t ws_size,
                              hipStream_t stream){
    const float* x      = (const float*)d_in[0];
    const int*   ei     = (const int*)  d_in[1];
    const float* W1     = (const float*)d_in[2];
    const float* a_src1 = (const float*)d_in[3];
    const float* a_dst1 = (const float*)d_in[4];
    const float* b1     = (const float*)d_in[5];
    const float* W2     = (const float*)d_in[6];
    const float* a_src2 = (const float*)d_in[7];
    const float* a_dst2 = (const float*)d_in[8];
    const float* b2     = (const float*)d_in[9];
    float* out = (float*)d_out;

    int N  = in_sizes[0] / 128;
    int E  = in_sizes[1] / 2;
    int ET = E + N;
    int nScanBlk = (N + 1023) / 1024;
    int G  = (ET + 255) / 256;
    int GH = (ET + 4095) / 4096;
    int nGemmBlk = (N + 63) / 64;

    char* ws = (char*)d_ws;
    size_t off = 0;
    auto alloc = [&](size_t bytes) -> char* {
        char* p = ws + off;
        off += (bytes + 255) & ~(size_t)255;
        return p;
    };
    int*            degp    = (int*)           alloc((size_t)NPART * N * 4);
    int*            rowptr  = (int*)           alloc((size_t)(N + 1) * 4);
    int*            bsum    = (int*)           alloc((size_t)nScanBlk * 4);
    unsigned short* rank    = (unsigned short*)alloc((size_t)ET * 2);
    int*            poff    = (int*)           alloc((size_t)NPART * N * 4);
    int*            csr_src = (int*)           alloc((size_t)ET * 4);
    _Float16*       h1h     = (_Float16*)      alloc((size_t)N * 128 * 2);
    float*          x2      = (float*)         alloc((size_t)N * 128 * 4);
    float*          asrc1   = (float*)         alloc((size_t)N * 4 * 4);
    float*          adst1   = (float*)         alloc((size_t)N * 4 * 4);
    _Float16*       h2h     = (_Float16*)      alloc((size_t)N * 32 * 2);
    float*          asrc2   = (float*)         alloc((size_t)N * 4);
    float*          adst2   = (float*)         alloc((size_t)N * 4);
    _Float16*       W1f     = (_Float16*)      alloc((size_t)32 * 512 * 2);   // 32 KB
    _Float16*       Uf      = (_Float16*)      alloc((size_t)4 * 512 * 2);    // 4 KB
    _Float16*       W2f     = (_Float16*)      alloc((size_t)8 * 512 * 2);    // 8 KB
    _Float16*       U2f     = (_Float16*)      alloc((size_t)4 * 512 * 2);    // 4 KB

    hipMemsetAsync(degp, 0, (size_t)NPART * N * 4, stream);
    hipLaunchKernelGGL(k_pack,       dim3(42), dim3(256), 0, stream,
                       W1, a_src1, a_dst1, W2, a_src2, a_dst2, W1f, Uf, W2f, U2f);
    hipLaunchKernelGGL(k_gemm1_hist, dim3(GH + nGemmBlk), dim3(256), 0, stream,
                       x, W1f, Uf, h1h, asrc1, adst1, N, GH,
                       ei, E, ET, (unsigned int*)degp, rank);
    hipLaunchKernelGGL(k_scan_blk,  dim3(nScanBlk), dim3(256), 0, stream, degp, N, rowptr, bsum);
    hipLaunchKernelGGL(k_finalize,  dim3((N + 255) / 256), dim3(256), 0, stream, bsum, degp, N, ET, rowptr, poff);
    hipLaunchKernelGGL(k_scatter2,  dim3(G), dim3(256), 0, stream, ei, E, ET, N, poff, rank, csr_src);
    hipLaunchKernelGGL(k_agg1,      dim3((N + 15) / 16), dim3(256), 0, stream, rowptr, csr_src, asrc1, adst1, h1h, b1, x2, N);
    hipLaunchKernelGGL(k_gemm2,     dim3((N + 63) / 64), dim3(256), 0, stream, x2, W2f, U2f, h2h, asrc2, adst2, N);
    hipLaunchKernelGGL(k_agg2,      dim3((N + 31) / 32), dim3(256), 0, stream, rowptr, csr_src, asrc2, adst2, h2h, b2, out, N);
}